// Round 1
// baseline (149.950 us; speedup 1.0000x reference)
//
#include <hip/hip_runtime.h>

// RecursiveNN: 11-level binary tree reduction, shared linear map W(128x256)+b.
// Strategy: bf16 MFMA 16x16x32. Kernel1 fuses levels 1-6 (64-leaf subtree per
// block, LDS ping-pong). Kernel2 fuses levels 7-11. W fragments live in
// registers (each wave owns 2 N-tiles), pre-packed to lane order by pack_w.

typedef __bf16 bf16x8 __attribute__((ext_vector_type(8)));
typedef float f32x4 __attribute__((ext_vector_type(4)));

#define STRIDE 136  // 128 cols + 8 pad (ushorts) -> 272B rows, 16B-aligned cols

__device__ __forceinline__ unsigned short bf16rne(float x) {
    union { float f; unsigned int u; } v; v.f = x;
    unsigned int u = v.u;
    u += 0x7fffu + ((u >> 16) & 1u);   // round-to-nearest-even
    return (unsigned short)(u >> 16);
}

// Pack W (fp32 128x256, W[o][d]) into per-lane MFMA B-fragment order (bf16).
// Fragment f = nl*8 + kk for wave wv, lane l:
//   elem j = W[o][d+j], o = (2*wv+nl)*16 + (l&15), d = kk*32 + (l>>4)*8
// Stored at wpack[(f*256 + wv*64 + l)*8 ..+7] so the main kernels load it with
// 16 coalesced dwordx4 reads per thread.
__global__ void pack_w_kernel(const float* __restrict__ W,
                              unsigned short* __restrict__ wpack) {
    const int f = blockIdx.x;      // 0..15
    const int tid = threadIdx.x;   // 0..255 = wv*64 + l
    const int wv = tid >> 6, l = tid & 63;
    const int nl = f >> 3, kk = f & 7;
    const int o = ((wv << 1) + nl) * 16 + (l & 15);
    const int d = kk * 32 + ((l >> 4) << 3);
    const float* src = W + o * 256 + d;
    unsigned short h[8];
#pragma unroll
    for (int j = 0; j < 8; ++j) h[j] = bf16rne(src[j]);
    uint4* dst = (uint4*)(wpack + (size_t)(f * 256 + tid) * 8);
    *dst = *(const uint4*)h;
}

// Kernel 1: one block = one 64-leaf subtree of one batch. Gather leaves from
// embedding -> bf16 LDS, run 6 levels (64->32->16->8->4->2->1), write the
// single surviving node (bf16) to y[batch][sub][128].
__global__ __launch_bounds__(256) void tree64_kernel(
    const int* __restrict__ wid, const float* __restrict__ emb,
    const unsigned short* __restrict__ wpack, const float* __restrict__ bias,
    unsigned short* __restrict__ yout)
{
    __shared__ __align__(16) unsigned short buf[2][64 * STRIDE];  // ~34.8 KB
    __shared__ int ids[64];
    const int tid = threadIdx.x;
    const int blk = blockIdx.x;
    const int batch = blk >> 5;    // /32 subtrees
    const int sub = blk & 31;
    const int wv = tid >> 6;       // wave id: owns output cols 32*wv..+31
    const int ln = tid & 63;
    const int q = ln >> 4;         // quad
    const int lm = ln & 15;

    if (tid < 64) ids[tid] = wid[batch * 2048 + sub * 64 + tid];

    // W fragments: 16 x (8 bf16) = 64 VGPRs, coalesced from packed layout.
    bf16x8 wf[16];
    const bf16x8* wp = (const bf16x8*)wpack;
#pragma unroll
    for (int f = 0; f < 16; ++f) wf[f] = wp[f * 256 + tid];

    float bval[2];
    bval[0] = bias[(2 * wv + 0) * 16 + lm];
    bval[1] = bias[(2 * wv + 1) * 16 + lm];

    __syncthreads();  // ids visible

    // Gather 64 rows x 128 fp32 -> bf16 LDS. 2048 float4 chunks / 256 threads.
#pragma unroll
    for (int i = 0; i < 8; ++i) {
        const int flat = tid + 256 * i;
        const int row = flat >> 5;   // 32 float4 per row
        const int c4 = flat & 31;
        const float4 v = *(const float4*)(emb + (size_t)ids[row] * 128 + c4 * 4);
        ushort4 h;
        h.x = bf16rne(v.x); h.y = bf16rne(v.y);
        h.z = bf16rne(v.z); h.w = bf16rne(v.w);
        *(ushort4*)&buf[0][row * STRIDE + c4 * 4] = h;
    }
    __syncthreads();

    int nin = 64;
    int rb = 0;
    while (nin > 1) {
        const int nout = nin >> 1;
        const int ntm = (nout + 15) >> 4;   // M-tiles of 16 nodes
        for (int mt = 0; mt < ntm; ++mt) {
            const int m = mt * 16 + lm;     // node index (A row)
            // A fragments: pair[m][k] = buf[2m + (k>=128)][k&127]
            bf16x8 af[8];
#pragma unroll
            for (int kk = 0; kk < 8; ++kk) {
                const int k = kk * 32 + q * 8;
                const int row = 2 * m + (k >> 7);
                const int col = k & 127;
                af[kk] = *(const bf16x8*)&buf[rb][row * STRIDE + col];
            }
#pragma unroll
            for (int nl = 0; nl < 2; ++nl) {
                f32x4 acc = { bval[nl], bval[nl], bval[nl], bval[nl] };
#pragma unroll
                for (int kk = 0; kk < 8; ++kk)
                    acc = __builtin_amdgcn_mfma_f32_16x16x32_bf16(
                        af[kk], wf[nl * 8 + kk], acc, 0, 0, 0);
                const int col = (2 * wv + nl) * 16 + lm;  // D col = lane&15
                if (nout == 1) {
                    // last level: row 0 lives in quad 0, reg 0
                    if (q == 0)
                        yout[(size_t)(batch * 32 + sub) * 128 + col] =
                            bf16rne(acc[0]);
                } else {
#pragma unroll
                    for (int r = 0; r < 4; ++r) {
                        const int row = mt * 16 + q * 4 + r;  // D row
                        if (row < nout)
                            buf[rb ^ 1][row * STRIDE + col] = bf16rne(acc[r]);
                    }
                }
            }
        }
        __syncthreads();
        rb ^= 1;
        nin = nout;
    }
}

// Kernel 2: one block = one batch; 32 nodes -> 5 levels -> fp32 output row.
__global__ __launch_bounds__(256) void tree32_kernel(
    const unsigned short* __restrict__ yin,
    const unsigned short* __restrict__ wpack, const float* __restrict__ bias,
    float* __restrict__ out)
{
    __shared__ __align__(16) unsigned short buf[2][32 * STRIDE];  // ~17.4 KB
    const int tid = threadIdx.x;
    const int batch = blockIdx.x;
    const int wv = tid >> 6, ln = tid & 63, q = ln >> 4, lm = ln & 15;

    bf16x8 wf[16];
    const bf16x8* wp = (const bf16x8*)wpack;
#pragma unroll
    for (int f = 0; f < 16; ++f) wf[f] = wp[f * 256 + tid];
    float bval[2];
    bval[0] = bias[(2 * wv + 0) * 16 + lm];
    bval[1] = bias[(2 * wv + 1) * 16 + lm];

    // load 32 rows x 128 bf16 (512 x 16B chunks, 2 per thread)
#pragma unroll
    for (int i = 0; i < 2; ++i) {
        const int flat = tid + 256 * i;
        const int row = flat >> 4;   // 16 chunks per row
        const int c8 = flat & 15;
        const bf16x8 v =
            *(const bf16x8*)(yin + (size_t)(batch * 32 + row) * 128 + c8 * 8);
        *(bf16x8*)&buf[0][row * STRIDE + c8 * 8] = v;
    }
    __syncthreads();

    int nin = 32, rb = 0;
    while (nin > 1) {
        const int nout = nin >> 1;   // 16,8,4,2,1 -> always a single M-tile
        const int m = lm;
        bf16x8 af[8];
#pragma unroll
        for (int kk = 0; kk < 8; ++kk) {
            const int k = kk * 32 + q * 8;
            const int row = 2 * m + (k >> 7);
            const int col = k & 127;
            af[kk] = *(const bf16x8*)&buf[rb][row * STRIDE + col];
        }
#pragma unroll
        for (int nl = 0; nl < 2; ++nl) {
            f32x4 acc = { bval[nl], bval[nl], bval[nl], bval[nl] };
#pragma unroll
            for (int kk = 0; kk < 8; ++kk)
                acc = __builtin_amdgcn_mfma_f32_16x16x32_bf16(
                    af[kk], wf[nl * 8 + kk], acc, 0, 0, 0);
            const int col = (2 * wv + nl) * 16 + lm;
            if (nout == 1) {
                if (q == 0) out[(size_t)batch * 128 + col] = acc[0];  // fp32
            } else {
#pragma unroll
                for (int r = 0; r < 4; ++r) {
                    const int row = q * 4 + r;
                    if (row < nout)
                        buf[rb ^ 1][row * STRIDE + col] = bf16rne(acc[r]);
                }
            }
        }
        __syncthreads();
        rb ^= 1;
        nin = nout;
    }
}

extern "C" void kernel_launch(void* const* d_in, const int* in_sizes, int n_in,
                              void* d_out, int out_size, void* d_ws, size_t ws_size,
                              hipStream_t stream) {
    const int*   wid = (const int*)d_in[0];      // (256, 2048) int32
    const float* emb = (const float*)d_in[1];    // (100000, 128) fp32
    const float* W   = (const float*)d_in[2];    // (128, 256) fp32
    const float* b   = (const float*)d_in[3];    // (128,) fp32
    float* out = (float*)d_out;                  // (256, 128) fp32

    unsigned short* wpack = (unsigned short*)d_ws;   // 32768 ushorts = 64 KB
    unsigned short* y     = wpack + 32768;           // (256,32,128) bf16 = 2 MB

    pack_w_kernel<<<16, 256, 0, stream>>>(W, wpack);
    tree64_kernel<<<8192, 256, 0, stream>>>(wid, emb, wpack, b, y);
    tree32_kernel<<<256, 256, 0, stream>>>(y, wpack, b, out);
}

// Round 2
// 146.676 us; speedup vs baseline: 1.0223x; 1.0223x over previous
//
#include <hip/hip_runtime.h>

// RecursiveNN: 11-level binary tree, shared linear map W(128x256)+b, bf16 MFMA.
// prep: W -> per-lane MFMA B-fragments (bf16), embedding table fp32 -> bf16.
// tree64: one block = one 64-leaf subtree; gather bf16 rows -> LDS; 6 levels
//         of 16x16x32 MFMA with LDS ping-pong. W fragments live in registers.
// tree32: one block = one batch; final 5 levels; fp32 output.
// All f32->bf16 via __builtin_convertvector (native v_cvt_pk_bf16_f32, RNE).

typedef __bf16 bf16x8 __attribute__((ext_vector_type(8)));
typedef __bf16 bf16x4 __attribute__((ext_vector_type(4)));
typedef float f32x4 __attribute__((ext_vector_type(4)));
typedef float f32x8 __attribute__((ext_vector_type(8)));

#define STRIDE 136  // 128 cols + 8 pad bf16 -> 272B rows (16B-aligned cols)

// blocks 0..15: pack W into MFMA B-fragment lane order.
//   frag f=nl*8+kk, wave wv, lane l: elem j = W[o][d+j],
//   o=(2wv+nl)*16+(l&15), d=kk*32+(l>>4)*8; stored at wpack[(f*256+tid)*8].
// blocks 16..6265: convert embedding (100000x128 fp32) to bf16 (8 elems/thr).
__global__ __launch_bounds__(256) void prep_kernel(
    const float* __restrict__ W, const float* __restrict__ emb,
    __bf16* __restrict__ wpack, __bf16* __restrict__ ebf)
{
    const int tid = threadIdx.x;
    const int blk = blockIdx.x;
    if (blk < 16) {
        const int f = blk;
        const int wv = tid >> 6, l = tid & 63;
        const int nl = f >> 3, kk = f & 7;
        const int o = ((wv << 1) + nl) * 16 + (l & 15);
        const int d = kk * 32 + ((l >> 4) << 3);
        const float* src = W + o * 256 + d;
        bf16x8 h;
#pragma unroll
        for (int j = 0; j < 8; ++j) h[j] = (__bf16)src[j];
        *(bf16x8*)(wpack + (size_t)(f * 256 + tid) * 8) = h;
    } else {
        const size_t base = ((size_t)(blk - 16) * 256 + tid) * 8;  // < 12.8M
        const f32x8 v = *(const f32x8*)(emb + base);
        *(bf16x8*)(ebf + base) = __builtin_convertvector(v, bf16x8);
    }
}

// Legacy W-pack only (fallback path when ws is too small for the bf16 table).
__global__ void pack_w_kernel(const float* __restrict__ W,
                              __bf16* __restrict__ wpack) {
    const int f = blockIdx.x;
    const int tid = threadIdx.x;
    const int wv = tid >> 6, l = tid & 63;
    const int nl = f >> 3, kk = f & 7;
    const int o = ((wv << 1) + nl) * 16 + (l & 15);
    const int d = kk * 32 + ((l >> 4) << 3);
    const float* src = W + o * 256 + d;
    bf16x8 h;
#pragma unroll
    for (int j = 0; j < 8; ++j) h[j] = (__bf16)src[j];
    *(bf16x8*)(wpack + (size_t)(f * 256 + tid) * 8) = h;
}

// Shared 6-level tree body. buf[0] must hold the 64 gathered leaf rows.
__device__ __forceinline__ void tree64_levels(
    __bf16 (*buf)[64 * STRIDE], const bf16x8* wf, const float* bval,
    int wv, int q, int lm, __bf16* yrow)
{
    int nin = 64, rb = 0;
    while (nin > 1) {
        const int nout = nin >> 1;
        const int ntm = (nout + 15) >> 4;
        for (int mt = 0; mt < ntm; ++mt) {
            const int m = mt * 16 + lm;
            bf16x8 af[8];
#pragma unroll
            for (int kk = 0; kk < 8; ++kk) {
                const int k = kk * 32 + q * 8;
                const int row = 2 * m + (k >> 7);
                const int col = k & 127;
                af[kk] = *(const bf16x8*)&buf[rb][row * STRIDE + col];
            }
#pragma unroll
            for (int nl = 0; nl < 2; ++nl) {
                f32x4 acc = { bval[nl], bval[nl], bval[nl], bval[nl] };
#pragma unroll
                for (int kk = 0; kk < 8; ++kk)
                    acc = __builtin_amdgcn_mfma_f32_16x16x32_bf16(
                        af[kk], wf[nl * 8 + kk], acc, 0, 0, 0);
                const int col = (2 * wv + nl) * 16 + lm;  // D col = lane&15
                if (nout == 1) {
                    if (q == 0) yrow[col] = (__bf16)acc[0];  // row0 = quad0,r0
                } else {
                    const bf16x4 hv = __builtin_convertvector(acc, bf16x4);
#pragma unroll
                    for (int r = 0; r < 4; ++r) {
                        const int row = mt * 16 + q * 4 + r;  // D row
                        if (row < nout)
                            buf[rb ^ 1][row * STRIDE + col] = hv[r];
                    }
                }
            }
        }
        __syncthreads();
        rb ^= 1;
        nin = nout;
    }
}

// Kernel 1 (bf16 table): one block = one 64-leaf subtree of one batch.
__global__ __launch_bounds__(256) void tree64_kernel(
    const int* __restrict__ wid, const __bf16* __restrict__ ebf,
    const __bf16* __restrict__ wpack, const float* __restrict__ bias,
    __bf16* __restrict__ yout)
{
    __shared__ __align__(16) __bf16 buf[2][64 * STRIDE];  // ~34.8 KB
    __shared__ int ids[64];
    const int tid = threadIdx.x;
    const int batch = blockIdx.x >> 5;
    const int sub = blockIdx.x & 31;
    const int wv = tid >> 6, ln = tid & 63, q = ln >> 4, lm = ln & 15;

    if (tid < 64) ids[tid] = wid[batch * 2048 + sub * 64 + tid];

    bf16x8 wf[16];
    const bf16x8* wp = (const bf16x8*)wpack;
#pragma unroll
    for (int f = 0; f < 16; ++f) wf[f] = wp[f * 256 + tid];
    float bval[2];
    bval[0] = bias[(2 * wv + 0) * 16 + lm];
    bval[1] = bias[(2 * wv + 1) * 16 + lm];

    __syncthreads();  // ids visible

    // Gather 64 rows x 128 bf16: 1024 x 16B chunks, 4 per thread. No cvt.
#pragma unroll
    for (int i = 0; i < 4; ++i) {
        const int flat = tid + 256 * i;
        const int row = flat >> 4;
        const int c8 = flat & 15;
        const bf16x8 v = *(const bf16x8*)(ebf + (size_t)ids[row] * 128 + c8 * 8);
        *(bf16x8*)&buf[0][row * STRIDE + c8 * 8] = v;
    }
    __syncthreads();

    tree64_levels(buf, wf, bval, wv, q, lm,
                  yout + (size_t)(batch * 32 + sub) * 128);
}

// Kernel 1 fallback (fp32 table gather + cvt), used if ws too small.
__global__ __launch_bounds__(256) void tree64_f32_kernel(
    const int* __restrict__ wid, const float* __restrict__ emb,
    const __bf16* __restrict__ wpack, const float* __restrict__ bias,
    __bf16* __restrict__ yout)
{
    __shared__ __align__(16) __bf16 buf[2][64 * STRIDE];
    __shared__ int ids[64];
    const int tid = threadIdx.x;
    const int batch = blockIdx.x >> 5;
    const int sub = blockIdx.x & 31;
    const int wv = tid >> 6, ln = tid & 63, q = ln >> 4, lm = ln & 15;

    if (tid < 64) ids[tid] = wid[batch * 2048 + sub * 64 + tid];

    bf16x8 wf[16];
    const bf16x8* wp = (const bf16x8*)wpack;
#pragma unroll
    for (int f = 0; f < 16; ++f) wf[f] = wp[f * 256 + tid];
    float bval[2];
    bval[0] = bias[(2 * wv + 0) * 16 + lm];
    bval[1] = bias[(2 * wv + 1) * 16 + lm];

    __syncthreads();

#pragma unroll
    for (int i = 0; i < 8; ++i) {
        const int flat = tid + 256 * i;
        const int row = flat >> 5;
        const int c4 = flat & 31;
        const f32x4 v = *(const f32x4*)(emb + (size_t)ids[row] * 128 + c4 * 4);
        *(bf16x4*)&buf[0][row * STRIDE + c4 * 4] =
            __builtin_convertvector(v, bf16x4);
    }
    __syncthreads();

    tree64_levels(buf, wf, bval, wv, q, lm,
                  yout + (size_t)(batch * 32 + sub) * 128);
}

// Kernel 2: one block = one batch; 32 subtree roots -> 5 levels -> fp32 row.
__global__ __launch_bounds__(256) void tree32_kernel(
    const __bf16* __restrict__ yin, const __bf16* __restrict__ wpack,
    const float* __restrict__ bias, float* __restrict__ out)
{
    __shared__ __align__(16) __bf16 buf[2][32 * STRIDE];  // ~17.4 KB
    const int tid = threadIdx.x;
    const int batch = blockIdx.x;
    const int wv = tid >> 6, ln = tid & 63, q = ln >> 4, lm = ln & 15;

    bf16x8 wf[16];
    const bf16x8* wp = (const bf16x8*)wpack;
#pragma unroll
    for (int f = 0; f < 16; ++f) wf[f] = wp[f * 256 + tid];
    float bval[2];
    bval[0] = bias[(2 * wv + 0) * 16 + lm];
    bval[1] = bias[(2 * wv + 1) * 16 + lm];

#pragma unroll
    for (int i = 0; i < 2; ++i) {
        const int flat = tid + 256 * i;
        const int row = flat >> 4;
        const int c8 = flat & 15;
        const bf16x8 v =
            *(const bf16x8*)(yin + (size_t)(batch * 32 + row) * 128 + c8 * 8);
        *(bf16x8*)&buf[0][row * STRIDE + c8 * 8] = v;
    }
    __syncthreads();

    int nin = 32, rb = 0;
    while (nin > 1) {
        const int nout = nin >> 1;
        const int m = lm;
        bf16x8 af[8];
#pragma unroll
        for (int kk = 0; kk < 8; ++kk) {
            const int k = kk * 32 + q * 8;
            const int row = 2 * m + (k >> 7);
            const int col = k & 127;
            af[kk] = *(const bf16x8*)&buf[rb][row * STRIDE + col];
        }
#pragma unroll
        for (int nl = 0; nl < 2; ++nl) {
            f32x4 acc = { bval[nl], bval[nl], bval[nl], bval[nl] };
#pragma unroll
            for (int kk = 0; kk < 8; ++kk)
                acc = __builtin_amdgcn_mfma_f32_16x16x32_bf16(
                    af[kk], wf[nl * 8 + kk], acc, 0, 0, 0);
            const int col = (2 * wv + nl) * 16 + lm;
            if (nout == 1) {
                if (q == 0) out[(size_t)batch * 128 + col] = acc[0];
            } else {
                const bf16x4 hv = __builtin_convertvector(acc, bf16x4);
#pragma unroll
                for (int r = 0; r < 4; ++r) {
                    const int row = q * 4 + r;
                    if (row < nout)
                        buf[rb ^ 1][row * STRIDE + col] = hv[r];
                }
            }
        }
        __syncthreads();
        rb ^= 1;
        nin = nout;
    }
}

extern "C" void kernel_launch(void* const* d_in, const int* in_sizes, int n_in,
                              void* d_out, int out_size, void* d_ws, size_t ws_size,
                              hipStream_t stream) {
    const int*   wid = (const int*)d_in[0];      // (256, 2048) int32
    const float* emb = (const float*)d_in[1];    // (100000, 128) fp32
    const float* W   = (const float*)d_in[2];    // (128, 256) fp32
    const float* b   = (const float*)d_in[3];    // (128,) fp32
    float* out = (float*)d_out;                  // (256, 128) fp32

    __bf16* wpack = (__bf16*)d_ws;               // 32768 elems = 64 KB
    __bf16* ebf   = wpack + 32768;               // 12.8M elems = 25.6 MB
    __bf16* y     = ebf + 12800000;              // 1.05M elems = 2 MB
    const size_t need = (32768 + 12800000 + 256 * 32 * 128) * sizeof(__bf16);

    if (ws_size >= need) {
        prep_kernel<<<16 + 6250, 256, 0, stream>>>(W, emb, wpack, ebf);
        tree64_kernel<<<8192, 256, 0, stream>>>(wid, ebf, wpack, b, y);
        tree32_kernel<<<256, 256, 0, stream>>>(y, wpack, b, out);
    } else {
        __bf16* y2 = wpack + 32768;
        pack_w_kernel<<<16, 256, 0, stream>>>(W, wpack);
        tree64_f32_kernel<<<8192, 256, 0, stream>>>(wid, emb, wpack, b, y2);
        tree32_kernel<<<256, 256, 0, stream>>>(y2, wpack, b, out);
    }
}

// Round 3
// 139.068 us; speedup vs baseline: 1.0782x; 1.0547x over previous
//
#include <hip/hip_runtime.h>

// RecursiveNN: 11-level binary tree, shared linear map W(128x256)+b, bf16 MFMA.
// prep: W -> per-lane MFMA B-fragments (bf16), embedding table fp32 -> bf16.
// tree128: one block = 128 contiguous leaves; 6 fused levels (128->...->2) with
//          asymmetric LDS ping-pong (128-row + 64-row buffers). W fragments in
//          registers; A-reads clamp-predicated so padded rows broadcast row 0.
// tree32: one block = one batch; final 5 levels (32->1); fp32 output.

typedef __bf16 bf16x8 __attribute__((ext_vector_type(8)));
typedef __bf16 bf16x4 __attribute__((ext_vector_type(4)));
typedef float f32x4 __attribute__((ext_vector_type(4)));
typedef float f32x8 __attribute__((ext_vector_type(8)));

#define STRIDE 136  // 128 cols + 8 pad bf16 -> 272B rows (16B-aligned, no conflicts)

// blocks 0..15: pack W into MFMA B-fragment lane order.
//   frag f=nl*8+kk, wave wv, lane l: elem j = W[o][d+j],
//   o=(2wv+nl)*16+(l&15), d=kk*32+(l>>4)*8; stored at wpack[(f*256+tid)*8].
// blocks 16..6265: convert embedding (100000x128 fp32) to bf16 (8 elems/thr).
__global__ __launch_bounds__(256) void prep_kernel(
    const float* __restrict__ W, const float* __restrict__ emb,
    __bf16* __restrict__ wpack, __bf16* __restrict__ ebf)
{
    const int tid = threadIdx.x;
    const int blk = blockIdx.x;
    if (blk < 16) {
        const int f = blk;
        const int wv = tid >> 6, l = tid & 63;
        const int nl = f >> 3, kk = f & 7;
        const int o = ((wv << 1) + nl) * 16 + (l & 15);
        const int d = kk * 32 + ((l >> 4) << 3);
        const float* src = W + o * 256 + d;
        bf16x8 h;
#pragma unroll
        for (int j = 0; j < 8; ++j) h[j] = (__bf16)src[j];
        *(bf16x8*)(wpack + (size_t)(f * 256 + tid) * 8) = h;
    } else {
        const size_t base = ((size_t)(blk - 16) * 256 + tid) * 8;  // < 12.8M
        const f32x8 v = *(const f32x8*)(emb + base);
        *(bf16x8*)(ebf + base) = __builtin_convertvector(v, bf16x8);
    }
}

// Legacy W-pack only (fallback when ws too small for the bf16 table).
__global__ void pack_w_kernel(const float* __restrict__ W,
                              __bf16* __restrict__ wpack) {
    const int f = blockIdx.x;
    const int tid = threadIdx.x;
    const int wv = tid >> 6, l = tid & 63;
    const int nl = f >> 3, kk = f & 7;
    const int o = ((wv << 1) + nl) * 16 + (l & 15);
    const int d = kk * 32 + ((l >> 4) << 3);
    const float* src = W + o * 256 + d;
    bf16x8 h;
#pragma unroll
    for (int j = 0; j < 8; ++j) h[j] = (__bf16)src[j];
    *(bf16x8*)(wpack + (size_t)(f * 256 + tid) * 8) = h;
}

// 6 fused levels on 128 leaf rows sitting in bufA; writes 2 root rows to yrow.
__device__ __forceinline__ void tree128_levels(
    __bf16* bufA, __bf16* bufB, const bf16x8* wf, const float* bval,
    int wv, int q, int lm, __bf16* yrow)
{
    int nin = 128, rb = 0;
    while (nin > 2) {
        const int nout = nin >> 1;
        const __bf16* src = rb ? bufB : bufA;
        __bf16* dst = rb ? bufA : bufB;
        const int ntm = (nout + 15) >> 4;
        for (int mt = 0; mt < ntm; ++mt) {
            const int m = mt * 16 + lm;
            // clamp: invalid lanes broadcast row 0 (free, avoids padded traffic)
            const int me = (m < nout) ? m : 0;
            bf16x8 af[8];
#pragma unroll
            for (int kk = 0; kk < 8; ++kk) {
                const int k = kk * 32 + q * 8;
                const int row = 2 * me + (k >> 7);
                const int col = k & 127;
                af[kk] = *(const bf16x8*)&src[row * STRIDE + col];
            }
#pragma unroll
            for (int nl = 0; nl < 2; ++nl) {
                f32x4 acc = { bval[nl], bval[nl], bval[nl], bval[nl] };
#pragma unroll
                for (int kk = 0; kk < 8; ++kk)
                    acc = __builtin_amdgcn_mfma_f32_16x16x32_bf16(
                        af[kk], wf[nl * 8 + kk], acc, 0, 0, 0);
                const int col = (2 * wv + nl) * 16 + lm;  // D col = lane&15
                if (nout == 2) {
                    // final level: rows 0,1 = quad 0, regs 0,1 -> global bf16
                    if (q == 0) {
                        yrow[0 * 128 + col] = (__bf16)acc[0];
                        yrow[1 * 128 + col] = (__bf16)acc[1];
                    }
                } else {
                    const bf16x4 hv = __builtin_convertvector(acc, bf16x4);
#pragma unroll
                    for (int r = 0; r < 4; ++r) {
                        const int row = mt * 16 + q * 4 + r;  // D row
                        if (row < nout)
                            dst[row * STRIDE + col] = hv[r];
                    }
                }
            }
        }
        __syncthreads();
        rb ^= 1;
        nin = nout;
    }
}

// Kernel 1 (bf16 table): one block = 128 contiguous leaves of one batch.
__global__ __launch_bounds__(256) void tree128_kernel(
    const int* __restrict__ wid, const __bf16* __restrict__ ebf,
    const __bf16* __restrict__ wpack, const float* __restrict__ bias,
    __bf16* __restrict__ yout)
{
    __shared__ __align__(16) __bf16 bufA[128 * STRIDE];  // 34.0 KB
    __shared__ __align__(16) __bf16 bufB[64 * STRIDE];   // 17.0 KB
    __shared__ int ids[128];
    const int tid = threadIdx.x;
    const int batch = blockIdx.x >> 4;   // 16 groups of 128 leaves per batch
    const int grp = blockIdx.x & 15;
    const int wv = tid >> 6, ln = tid & 63, q = ln >> 4, lm = ln & 15;

    if (tid < 128) ids[tid] = wid[batch * 2048 + grp * 128 + tid];

    bf16x8 wf[16];
    const bf16x8* wp = (const bf16x8*)wpack;
#pragma unroll
    for (int f = 0; f < 16; ++f) wf[f] = wp[f * 256 + tid];
    float bval[2];
    bval[0] = bias[(2 * wv + 0) * 16 + lm];
    bval[1] = bias[(2 * wv + 1) * 16 + lm];

    __syncthreads();  // ids visible

    // Gather 128 rows x 128 bf16: 2048 x 16B chunks, 8 per thread. Coalesced
    // 256B per row across 16 consecutive threads.
#pragma unroll
    for (int i = 0; i < 8; ++i) {
        const int flat = tid + 256 * i;
        const int row = flat >> 4;
        const int c8 = flat & 15;
        const bf16x8 v = *(const bf16x8*)(ebf + (size_t)ids[row] * 128 + c8 * 8);
        *(bf16x8*)&bufA[row * STRIDE + c8 * 8] = v;
    }
    __syncthreads();

    tree128_levels(bufA, bufB, wf, bval, wv, q, lm,
                   yout + (size_t)(batch * 32 + grp * 2) * 128);
}

// Kernel 1 fallback (fp32 table gather + cvt), used if ws too small.
__global__ __launch_bounds__(256) void tree128_f32_kernel(
    const int* __restrict__ wid, const float* __restrict__ emb,
    const __bf16* __restrict__ wpack, const float* __restrict__ bias,
    __bf16* __restrict__ yout)
{
    __shared__ __align__(16) __bf16 bufA[128 * STRIDE];
    __shared__ __align__(16) __bf16 bufB[64 * STRIDE];
    __shared__ int ids[128];
    const int tid = threadIdx.x;
    const int batch = blockIdx.x >> 4;
    const int grp = blockIdx.x & 15;
    const int wv = tid >> 6, ln = tid & 63, q = ln >> 4, lm = ln & 15;

    if (tid < 128) ids[tid] = wid[batch * 2048 + grp * 128 + tid];

    bf16x8 wf[16];
    const bf16x8* wp = (const bf16x8*)wpack;
#pragma unroll
    for (int f = 0; f < 16; ++f) wf[f] = wp[f * 256 + tid];
    float bval[2];
    bval[0] = bias[(2 * wv + 0) * 16 + lm];
    bval[1] = bias[(2 * wv + 1) * 16 + lm];

    __syncthreads();

#pragma unroll
    for (int i = 0; i < 16; ++i) {
        const int flat = tid + 256 * i;
        const int row = flat >> 5;
        const int c4 = flat & 31;
        const f32x4 v = *(const f32x4*)(emb + (size_t)ids[row] * 128 + c4 * 4);
        *(bf16x4*)&bufA[row * STRIDE + c4 * 4] =
            __builtin_convertvector(v, bf16x4);
    }
    __syncthreads();

    tree128_levels(bufA, bufB, wf, bval, wv, q, lm,
                   yout + (size_t)(batch * 32 + grp * 2) * 128);
}

// Kernel 2: one block = one batch; 32 subtree roots -> 5 levels -> fp32 row.
__global__ __launch_bounds__(256) void tree32_kernel(
    const __bf16* __restrict__ yin, const __bf16* __restrict__ wpack,
    const float* __restrict__ bias, float* __restrict__ out)
{
    __shared__ __align__(16) __bf16 buf[2][32 * STRIDE];  // ~17.4 KB
    const int tid = threadIdx.x;
    const int batch = blockIdx.x;
    const int wv = tid >> 6, ln = tid & 63, q = ln >> 4, lm = ln & 15;

    bf16x8 wf[16];
    const bf16x8* wp = (const bf16x8*)wpack;
#pragma unroll
    for (int f = 0; f < 16; ++f) wf[f] = wp[f * 256 + tid];
    float bval[2];
    bval[0] = bias[(2 * wv + 0) * 16 + lm];
    bval[1] = bias[(2 * wv + 1) * 16 + lm];

#pragma unroll
    for (int i = 0; i < 2; ++i) {
        const int flat = tid + 256 * i;
        const int row = flat >> 4;
        const int c8 = flat & 15;
        const bf16x8 v =
            *(const bf16x8*)(yin + (size_t)(batch * 32 + row) * 128 + c8 * 8);
        *(bf16x8*)&buf[0][row * STRIDE + c8 * 8] = v;
    }
    __syncthreads();

    int nin = 32, rb = 0;
    while (nin > 1) {
        const int nout = nin >> 1;
        const int m = lm;
        const int me = (m < nout) ? m : 0;
        bf16x8 af[8];
#pragma unroll
        for (int kk = 0; kk < 8; ++kk) {
            const int k = kk * 32 + q * 8;
            const int row = 2 * me + (k >> 7);
            const int col = k & 127;
            af[kk] = *(const bf16x8*)&buf[rb][row * STRIDE + col];
        }
#pragma unroll
        for (int nl = 0; nl < 2; ++nl) {
            f32x4 acc = { bval[nl], bval[nl], bval[nl], bval[nl] };
#pragma unroll
            for (int kk = 0; kk < 8; ++kk)
                acc = __builtin_amdgcn_mfma_f32_16x16x32_bf16(
                    af[kk], wf[nl * 8 + kk], acc, 0, 0, 0);
            const int col = (2 * wv + nl) * 16 + lm;
            if (nout == 1) {
                if (q == 0) out[(size_t)batch * 128 + col] = acc[0];
            } else {
                const bf16x4 hv = __builtin_convertvector(acc, bf16x4);
#pragma unroll
                for (int r = 0; r < 4; ++r) {
                    const int row = q * 4 + r;
                    if (row < nout)
                        buf[rb ^ 1][row * STRIDE + col] = hv[r];
                }
            }
        }
        __syncthreads();
        rb ^= 1;
        nin = nout;
    }
}

extern "C" void kernel_launch(void* const* d_in, const int* in_sizes, int n_in,
                              void* d_out, int out_size, void* d_ws, size_t ws_size,
                              hipStream_t stream) {
    const int*   wid = (const int*)d_in[0];      // (256, 2048) int32
    const float* emb = (const float*)d_in[1];    // (100000, 128) fp32
    const float* W   = (const float*)d_in[2];    // (128, 256) fp32
    const float* b   = (const float*)d_in[3];    // (128,) fp32
    float* out = (float*)d_out;                  // (256, 128) fp32

    __bf16* wpack = (__bf16*)d_ws;               // 32768 elems = 64 KB
    __bf16* ebf   = wpack + 32768;               // 12.8M elems = 25.6 MB
    __bf16* y     = ebf + 12800000;              // (256,32,128) bf16 = 2 MB
    const size_t need = (32768 + 12800000 + 256 * 32 * 128) * sizeof(__bf16);

    if (ws_size >= need) {
        prep_kernel<<<16 + 6250, 256, 0, stream>>>(W, emb, wpack, ebf);
        tree128_kernel<<<4096, 256, 0, stream>>>(wid, ebf, wpack, b, y);
        tree32_kernel<<<256, 256, 0, stream>>>(y, wpack, b, out);
    } else {
        __bf16* y2 = wpack + 32768;
        pack_w_kernel<<<16, 256, 0, stream>>>(W, wpack);
        tree128_f32_kernel<<<4096, 256, 0, stream>>>(wid, emb, wpack, b, y2);
        tree32_kernel<<<256, 256, 0, stream>>>(y2, wpack, b, out);
    }
}

// Round 4
// 130.875 us; speedup vs baseline: 1.1457x; 1.0626x over previous
//
#include <hip/hip_runtime.h>

// RecursiveNN: 11-level binary tree, shared linear map W(128x256)+b, bf16 MFMA.
// pack_w: W -> per-lane MFMA B-fragment order (bf16), 64 KB in ws.
// tree128: one block = 128 contiguous leaves; fp32 gather + packed cvt -> LDS;
//   7 fused level-steps (128->2) with scratch rotation in 43.5 KB LDS
//   (bufA 128 rows + bufB 32 rows -> 3 blocks/CU on the 128 KB usable pool).
//   W fragments live in registers (each wave owns 2 of 8 N-tiles).
// tree32: one block = one batch; final 5 levels (32->1); fp32 output.

typedef __bf16 bf16x8 __attribute__((ext_vector_type(8)));
typedef __bf16 bf16x4 __attribute__((ext_vector_type(4)));
typedef float f32x4 __attribute__((ext_vector_type(4)));

#define STRIDE 136  // 128 cols + 8 pad bf16 = 272B rows; 0 LDS conflicts measured

// Pack W (fp32 128x256) into MFMA B-fragment lane order (bf16):
//   frag f=nl*8+kk, wave wv, lane l: elem j = W[o][d+j],
//   o=(2wv+nl)*16+(l&15), d=kk*32+(l>>4)*8; stored at wpack[(f*256+tid)*8].
__global__ void pack_w_kernel(const float* __restrict__ W,
                              __bf16* __restrict__ wpack) {
    const int f = blockIdx.x;
    const int tid = threadIdx.x;
    const int wv = tid >> 6, l = tid & 63;
    const int nl = f >> 3, kk = f & 7;
    const int o = ((wv << 1) + nl) * 16 + (l & 15);
    const int d = kk * 32 + ((l >> 4) << 3);
    const float* src = W + o * 256 + d;
    bf16x8 h;
#pragma unroll
    for (int j = 0; j < 8; ++j) h[j] = (__bf16)src[j];
    *(bf16x8*)(wpack + (size_t)(f * 256 + tid) * 8) = h;
}

// One level-step: NOUT local outputs from 2*NOUT local input rows.
// src0 = rows 0..31, src1 = rows 32..63 (unused when NOUT<=16). Ends in barrier.
template <int NOUT>
__device__ __forceinline__ void level_step(
    const __bf16* src0, const __bf16* src1, __bf16* dst,
    const bf16x8* wf, const float* bval, int wv, int q, int lm)
{
    const int ntm = (NOUT + 15) >> 4;
#pragma unroll
    for (int mt = 0; mt < ntm; ++mt) {
        const __bf16* src = mt ? src1 : src0;
        // clamp: padded lanes broadcast row 0/1 (free; no garbage traffic)
        const int me = (NOUT >= 16) ? lm : (lm < NOUT ? lm : 0);
        bf16x8 af[8];
#pragma unroll
        for (int kk = 0; kk < 8; ++kk) {
            const int hi = kk >> 2;                   // k >= 128 half
            const int col = (kk & 3) * 32 + q * 8;
            const int row = 2 * me + hi;              // local row 0..31
            af[kk] = *(const bf16x8*)&src[row * STRIDE + col];
        }
#pragma unroll
        for (int nl = 0; nl < 2; ++nl) {
            f32x4 acc = { bval[nl], bval[nl], bval[nl], bval[nl] };
#pragma unroll
            for (int kk = 0; kk < 8; ++kk)
                acc = __builtin_amdgcn_mfma_f32_16x16x32_bf16(
                    af[kk], wf[nl * 8 + kk], acc, 0, 0, 0);
            const int col = (2 * wv + nl) * 16 + lm;  // D col = lane&15
            const bf16x4 hv = __builtin_convertvector(acc, bf16x4);
#pragma unroll
            for (int r = 0; r < 4; ++r) {
                const int row = mt * 16 + q * 4 + r;  // D row
                if (row < NOUT)
                    dst[row * STRIDE + col] = hv[r];
            }
        }
    }
    __syncthreads();
}

// Final step: 4 input rows -> 2 roots straight to global (bf16).
__device__ __forceinline__ void level_final(
    const __bf16* src, __bf16* yrow,
    const bf16x8* wf, const float* bval, int wv, int q, int lm)
{
    const int me = (lm < 2) ? lm : 0;
    bf16x8 af[8];
#pragma unroll
    for (int kk = 0; kk < 8; ++kk) {
        const int hi = kk >> 2;
        const int col = (kk & 3) * 32 + q * 8;
        af[kk] = *(const bf16x8*)&src[(2 * me + hi) * STRIDE + col];
    }
#pragma unroll
    for (int nl = 0; nl < 2; ++nl) {
        f32x4 acc = { bval[nl], bval[nl], bval[nl], bval[nl] };
#pragma unroll
        for (int kk = 0; kk < 8; ++kk)
            acc = __builtin_amdgcn_mfma_f32_16x16x32_bf16(
                af[kk], wf[nl * 8 + kk], acc, 0, 0, 0);
        const int col = (2 * wv + nl) * 16 + lm;
        if (q == 0) {                 // rows 0,1 = quad 0 regs 0,1
            yrow[0 * 128 + col] = (__bf16)acc[0];
            yrow[1 * 128 + col] = (__bf16)acc[1];
        }
    }
}

// Kernel 1: one block = 128 contiguous leaves of one batch. fp32 gather with
// packed cvt; 7 level-steps with scratch rotation:
//   L1a: A[0:63]  -> B[0:31]    L1b: A[64:127]-> A[0:31]
//   L2:  B+A[0:31]-> A[32:63]   L3:  A[32:63] -> B[0:15]
//   L4:  B[0:15]  -> A[0:7]     L5:  A[0:7]   -> B[0:3]
//   L6:  B[0:3]   -> global roots (2 rows)
__global__ __launch_bounds__(256, 3) void tree128_kernel(
    const int* __restrict__ wid, const float* __restrict__ emb,
    const __bf16* __restrict__ wpack, const float* __restrict__ bias,
    __bf16* __restrict__ yout)
{
    __shared__ __align__(16) __bf16 bufA[128 * STRIDE];  // 34 KB
    __shared__ __align__(16) __bf16 bufB[32 * STRIDE];   // 8.5 KB -> 43.5 total
    const int tid = threadIdx.x;
    const int batch = blockIdx.x >> 4;   // 16 groups of 128 leaves per batch
    const int grp = blockIdx.x & 15;
    const int wv = tid >> 6, ln = tid & 63, q = ln >> 4, lm = ln & 15;

    // W fragments: 16 x (8 bf16) = 64 VGPRs, coalesced 256B per thread.
    bf16x8 wf[16];
    const bf16x8* wp = (const bf16x8*)wpack;
#pragma unroll
    for (int f = 0; f < 16; ++f) wf[f] = wp[f * 256 + tid];
    float bval[2];
    bval[0] = bias[(2 * wv + 0) * 16 + lm];
    bval[1] = bias[(2 * wv + 1) * 16 + lm];

    // Leaf ids in registers (32 lanes share each id -> broadcast loads).
    const int* wb = wid + batch * 2048 + grp * 128;
    int idreg[16];
#pragma unroll
    for (int i = 0; i < 16; ++i) idreg[i] = wb[(tid >> 5) + 8 * i];

    // Gather 128 rows x 128 fp32 -> bf16 LDS (coalesced 512B per row-group).
#pragma unroll
    for (int i = 0; i < 16; ++i) {
        const int row = (tid >> 5) + 8 * i;
        const int c4 = tid & 31;
        const f32x4 v = *(const f32x4*)(emb + (size_t)idreg[i] * 128 + c4 * 4);
        *(bf16x4*)&bufA[row * STRIDE + c4 * 4] =
            __builtin_convertvector(v, bf16x4);
    }
    __syncthreads();

    __bf16* A = bufA;
    __bf16* B = bufB;
    level_step<32>(A,               A + 32 * STRIDE, B,              wf, bval, wv, q, lm);
    level_step<32>(A + 64 * STRIDE, A + 96 * STRIDE, A,              wf, bval, wv, q, lm);
    level_step<32>(B,               A,               A + 32 * STRIDE,wf, bval, wv, q, lm);
    level_step<16>(A + 32 * STRIDE, nullptr,         B,              wf, bval, wv, q, lm);
    level_step<8> (B,               nullptr,         A,              wf, bval, wv, q, lm);
    level_step<4> (A,               nullptr,         B,              wf, bval, wv, q, lm);
    level_final(B, yout + (size_t)(batch * 32 + grp * 2) * 128,
                wf, bval, wv, q, lm);
}

// Kernel 2: one block = one batch; 32 subtree roots -> 5 levels -> fp32 row.
__global__ __launch_bounds__(256) void tree32_kernel(
    const __bf16* __restrict__ yin, const __bf16* __restrict__ wpack,
    const float* __restrict__ bias, float* __restrict__ out)
{
    __shared__ __align__(16) __bf16 buf[2][32 * STRIDE];  // ~17.4 KB
    const int tid = threadIdx.x;
    const int batch = blockIdx.x;
    const int wv = tid >> 6, ln = tid & 63, q = ln >> 4, lm = ln & 15;

    bf16x8 wf[16];
    const bf16x8* wp = (const bf16x8*)wpack;
#pragma unroll
    for (int f = 0; f < 16; ++f) wf[f] = wp[f * 256 + tid];
    float bval[2];
    bval[0] = bias[(2 * wv + 0) * 16 + lm];
    bval[1] = bias[(2 * wv + 1) * 16 + lm];

#pragma unroll
    for (int i = 0; i < 2; ++i) {
        const int flat = tid + 256 * i;
        const int row = flat >> 4;
        const int c8 = flat & 15;
        const bf16x8 v =
            *(const bf16x8*)(yin + (size_t)(batch * 32 + row) * 128 + c8 * 8);
        *(bf16x8*)&buf[0][row * STRIDE + c8 * 8] = v;
    }
    __syncthreads();

    int nin = 32, rb = 0;
    while (nin > 1) {
        const int nout = nin >> 1;
        const int me = (lm < nout) ? lm : 0;
        bf16x8 af[8];
#pragma unroll
        for (int kk = 0; kk < 8; ++kk) {
            const int hi = kk >> 2;
            const int col = (kk & 3) * 32 + q * 8;
            af[kk] = *(const bf16x8*)&buf[rb][(2 * me + hi) * STRIDE + col];
        }
#pragma unroll
        for (int nl = 0; nl < 2; ++nl) {
            f32x4 acc = { bval[nl], bval[nl], bval[nl], bval[nl] };
#pragma unroll
            for (int kk = 0; kk < 8; ++kk)
                acc = __builtin_amdgcn_mfma_f32_16x16x32_bf16(
                    af[kk], wf[nl * 8 + kk], acc, 0, 0, 0);
            const int col = (2 * wv + nl) * 16 + lm;
            if (nout == 1) {
                if (q == 0) out[(size_t)batch * 128 + col] = acc[0];
            } else {
                const bf16x4 hv = __builtin_convertvector(acc, bf16x4);
#pragma unroll
                for (int r = 0; r < 4; ++r) {
                    const int row = q * 4 + r;
                    if (row < nout)
                        buf[rb ^ 1][row * STRIDE + col] = hv[r];
                }
            }
        }
        __syncthreads();
        rb ^= 1;
        nin = nout;
    }
}

extern "C" void kernel_launch(void* const* d_in, const int* in_sizes, int n_in,
                              void* d_out, int out_size, void* d_ws, size_t ws_size,
                              hipStream_t stream) {
    const int*   wid = (const int*)d_in[0];      // (256, 2048) int32
    const float* emb = (const float*)d_in[1];    // (100000, 128) fp32
    const float* W   = (const float*)d_in[2];    // (128, 256) fp32
    const float* b   = (const float*)d_in[3];    // (128,) fp32
    float* out = (float*)d_out;                  // (256, 128) fp32

    __bf16* wpack = (__bf16*)d_ws;               // 32768 elems = 64 KB
    __bf16* y     = wpack + 32768;               // (256,32,128) bf16 = 2 MB

    pack_w_kernel<<<16, 256, 0, stream>>>(W, wpack);
    tree128_kernel<<<4096, 256, 0, stream>>>(wid, emb, wpack, b, y);
    tree32_kernel<<<256, 256, 0, stream>>>(y, wpack, b, out);
}